// Round 4
// baseline (32.590 us; speedup 1.0000x reference)
//
#include <hip/hip_runtime.h>

// ---------------------------------------------------------------------------
// HybridQFCModel, coalesced-staging structure:
//  k1 (qfc_main): block = 256 threads = 256 consecutive images. The used
//     region of each image (rows 0..5, cols 0..23 -> 36 float4s, 576 B) is
//     staged to LDS with global_load_lds in 4 groups of 64 images, double
//     buffered, with per-lane global addresses ascending -> streaming DRAM
//     pattern. Pooling: 4 threads/image from LDS (static reg indexing),
//     shfl_xor combine, enc stashed in LDS; then every thread runs the
//     4-qubit circuit for its own image. Block partials {sum o, sum o^2}.
//  k2 (qfc_stats_bn): every block redundantly reduces all partials in fixed
//     order (double) -> identical BN scale/shift, applies affine to its slice.
// ---------------------------------------------------------------------------

#define AS1 __attribute__((address_space(1)))
#define AS3 __attribute__((address_space(3)))

__device__ __forceinline__ void load_lds16(const float4* g, float4* l) {
    __builtin_amdgcn_global_load_lds((const AS1 void*)g, (AS3 void*)l, 16, 0, 0);
}

__global__ __launch_bounds__(256, 2) void qfc_main(
    const float* __restrict__ x,
    const float* __restrict__ qp,     // [2][4][2]
    float* __restrict__ out,          // [B][4] pre-BN
    float* __restrict__ partials)     // [gridDim.x][8]
{
    // stage[buf][p], p = img*36 + r*6 + q  (linear: required by global_load_lds)
    __shared__ float4 stage[2][2304];   // 2 x 36 KB
    __shared__ float4 encs[256];        // 4 KB
    __shared__ float  red[4][8];

    const int tid   = threadIdx.x;
    const int wid   = tid >> 6;
    const int lane  = tid & 63;
    const int gimg0 = blockIdx.x * 256;
    const float4* x4 = (const float4*)x;   // image stride 196, row stride 7

    // ---- issue group 0 into buf 0
    #pragma unroll
    for (int k = 0; k < 9; ++k) {
        const int sb  = k * 256 + wid * 64;      // wave-uniform LDS slot base
        const int p   = sb + lane;               // packed (img,r,q) index
        const int im  = p / 36;
        const int rq  = p - im * 36;
        const int r   = rq / 6;
        const int q   = rq - r * 6;
        load_lds16(x4 + (size_t)(gimg0 + im) * 196 + r * 7 + q, &stage[0][sb]);
    }
    __syncthreads();   // drains vmcnt(0): buf0 complete

    const int img = tid >> 2;   // 0..63 within group
    const int sub = tid & 3;    // 4 threads per image

    #pragma unroll
    for (int g = 0; g < 4; ++g) {
        const int cur = g & 1;
        // ---- issue group g+1 into the other buffer (async, hidden by pooling)
        if (g < 3) {
            const int nxt = cur ^ 1;
            #pragma unroll
            for (int k = 0; k < 9; ++k) {
                const int sb = k * 256 + wid * 64;
                const int p  = sb + lane;
                const int im = p / 36;
                const int rq = p - im * 36;
                const int r  = rq / 6;
                const int q  = rq - r * 6;
                load_lds16(x4 + (size_t)(gimg0 + (g + 1) * 64 + im) * 196 + r * 7 + q,
                           &stage[nxt][sb]);
            }
        }
        // ---- pool group g from buf[cur]: this thread owns slots sub*9..sub*9+8
        float enc0 = 0.f, enc1 = 0.f, enc2 = 0.f, enc3 = 0.f;
        #pragma unroll
        for (int i = 0; i < 9; ++i) {
            const int rq = sub * 9 + i;
            const int r  = rq / 6;
            const int q  = rq - r * 6;          // runtime, but enc regs static
            const float4 v = stage[cur][img * 36 + rq];
            const int c0 = q * 4;
            const int j0 = (c0 + 0) / 6, j1 = (c0 + 1) / 6;
            const int j2 = (c0 + 2) / 6, j3 = (c0 + 3) / 6;
            enc0 += (j0 == 0 ? v.x : 0.f) + (j1 == 0 ? v.y : 0.f) + (j2 == 0 ? v.z : 0.f) + (j3 == 0 ? v.w : 0.f);
            enc1 += (j0 == 1 ? v.x : 0.f) + (j1 == 1 ? v.y : 0.f) + (j2 == 1 ? v.z : 0.f) + (j3 == 1 ? v.w : 0.f);
            enc2 += (j0 == 2 ? v.x : 0.f) + (j1 == 2 ? v.y : 0.f) + (j2 == 2 ? v.z : 0.f) + (j3 == 2 ? v.w : 0.f);
            enc3 += (j0 == 3 ? v.x : 0.f) + (j1 == 3 ? v.y : 0.f) + (j2 == 3 ? v.z : 0.f) + (j3 == 3 ? v.w : 0.f);
        }
        // combine the 4 sub-threads (lane bits 0,1)
        enc0 += __shfl_xor(enc0, 1, 64); enc1 += __shfl_xor(enc1, 1, 64);
        enc2 += __shfl_xor(enc2, 1, 64); enc3 += __shfl_xor(enc3, 1, 64);
        enc0 += __shfl_xor(enc0, 2, 64); enc1 += __shfl_xor(enc1, 2, 64);
        enc2 += __shfl_xor(enc2, 2, 64); enc3 += __shfl_xor(enc3, 2, 64);
        if (sub == 0) {
            float4 e; e.x = enc0; e.y = enc1; e.z = enc2; e.w = enc3;
            encs[g * 64 + img] = e;
        }
        // waits lgkm (pool reads done -> safe to overwrite buf[cur] next iter)
        // and vmcnt(0) (group g+1 loads landed)
        __syncthreads();
    }

    // ---- circuit: one thread per image
    const float4 e = encs[tid];
    float enc[4] = { e.x, e.y, e.z, e.w };

    float ch[4], sh[4];
    #pragma unroll
    for (int w = 0; w < 4; ++w) {
        float h = enc[w] * (0.5f / 36.0f);
        __sincosf(h, &sh[w], &ch[w]);
    }

    float sr[16], si[16];
    #pragma unroll
    for (int idx = 0; idx < 16; ++idx) {
        float m = 1.f; int k = 0;
        #pragma unroll
        for (int w = 0; w < 4; ++w) {
            if ((idx >> (3 - w)) & 1) { m *= sh[w]; ++k; }
            else                        m *= ch[w];
        }
        switch (k & 3) {
            case 0:  sr[idx] =  m;  si[idx] = 0.f; break;
            case 1:  sr[idx] = 0.f; si[idx] = -m;  break;
            case 2:  sr[idx] = -m;  si[idx] = 0.f; break;
            default: sr[idx] = 0.f; si[idx] =  m;  break;
        }
    }

    #pragma unroll
    for (int l = 0; l < 2; ++l) {
        // RZ layer
        #pragma unroll
        for (int w = 0; w < 4; ++w) {
            float a = 0.5f * qp[l * 8 + w * 2 + 0];
            float sa, ca; __sincosf(a, &sa, &ca);
            #pragma unroll
            for (int idx = 0; idx < 16; ++idx) {
                float sg = ((idx >> (3 - w)) & 1) ? sa : -sa;
                float r = sr[idx], mm = si[idx];
                sr[idx] = r * ca - mm * sg;
                si[idx] = r * sg + mm * ca;
            }
        }
        // CNOT chain
        #pragma unroll
        for (int c = 0; c < 3; ++c) {
            const int t = c + 1;
            #pragma unroll
            for (int idx = 0; idx < 16; ++idx) {
                if ((((idx >> (3 - c)) & 1) == 1) && (((idx >> (3 - t)) & 1) == 0)) {
                    const int j = idx | (1 << (3 - t));
                    float tr = sr[idx]; sr[idx] = sr[j]; sr[j] = tr;
                    float ti = si[idx]; si[idx] = si[j]; si[j] = ti;
                }
            }
        }
        // RY layer
        #pragma unroll
        for (int w = 0; w < 4; ++w) {
            float bb = 0.5f * qp[l * 8 + w * 2 + 1];
            float sb, cb; __sincosf(bb, &sb, &cb);
            #pragma unroll
            for (int idx = 0; idx < 16; ++idx) {
                if (((idx >> (3 - w)) & 1) == 0) {
                    const int j = idx | (1 << (3 - w));
                    float r0 = sr[idx], r1 = sr[j];
                    sr[idx] = cb * r0 - sb * r1;
                    sr[j]   = sb * r0 + cb * r1;
                    float i0 = si[idx], i1 = si[j];
                    si[idx] = cb * i0 - sb * i1;
                    si[j]   = sb * i0 + cb * i1;
                }
            }
        }
    }

    // --- <Z_w>
    float o[4] = {0.f, 0.f, 0.f, 0.f};
    #pragma unroll
    for (int idx = 0; idx < 16; ++idx) {
        float p = sr[idx] * sr[idx] + si[idx] * si[idx];
        #pragma unroll
        for (int w = 0; w < 4; ++w)
            o[w] += ((idx >> (3 - w)) & 1) ? -p : p;
    }

    // --- pre-BN store (coalesced float4 per thread)
    const int b = gimg0 + tid;
    float4 ov; ov.x = o[0]; ov.y = o[1]; ov.z = o[2]; ov.w = o[3];
    ((float4*)out)[b] = ov;

    // --- per-block partial sums {o, o^2}
    float vals[8] = { o[0], o[1], o[2], o[3],
                      o[0]*o[0], o[1]*o[1], o[2]*o[2], o[3]*o[3] };
    #pragma unroll
    for (int q = 0; q < 8; ++q) {
        float v = vals[q];
        #pragma unroll
        for (int off = 32; off > 0; off >>= 1)
            v += __shfl_down(v, off, 64);
        vals[q] = v;
    }
    if (lane == 0) {
        #pragma unroll
        for (int q = 0; q < 8; ++q) red[wid][q] = vals[q];
    }
    __syncthreads();
    if (tid == 0) {
        #pragma unroll
        for (int q = 0; q < 8; ++q)
            partials[(size_t)blockIdx.x * 8 + q] =
                red[0][q] + red[1][q] + red[2][q] + red[3][q];
    }
}

// Every block redundantly reduces all partials (fixed order, double) ->
// identical stats; applies BN affine to its out slice.
__global__ __launch_bounds__(256) void qfc_stats_bn(
    const float* __restrict__ partials,
    const float* __restrict__ gamma,
    const float* __restrict__ beta,
    float* __restrict__ out,
    int nprt, int B)
{
    const int tid = threadIdx.x;
    double acc[8];
    #pragma unroll
    for (int q = 0; q < 8; ++q) acc[q] = 0.0;
    for (int r = tid; r < nprt; r += 256) {
        #pragma unroll
        for (int q = 0; q < 8; ++q) acc[q] += (double)partials[(size_t)r * 8 + q];
    }
    #pragma unroll
    for (int q = 0; q < 8; ++q) {
        double v = acc[q];
        #pragma unroll
        for (int off = 32; off > 0; off >>= 1)
            v += __shfl_down(v, off, 64);
        acc[q] = v;
    }
    __shared__ double dred[4][8];
    __shared__ float sstats[8];
    const int lane = tid & 63;
    const int wv   = tid >> 6;
    if (lane == 0) {
        #pragma unroll
        for (int q = 0; q < 8; ++q) dred[wv][q] = acc[q];
    }
    __syncthreads();
    if (tid == 0) {
        const double invB = 1.0 / (double)B;
        #pragma unroll
        for (int w = 0; w < 4; ++w) {
            double s  = dred[0][w]     + dred[1][w]     + dred[2][w]     + dred[3][w];
            double s2 = dred[0][4 + w] + dred[1][4 + w] + dred[2][4 + w] + dred[3][4 + w];
            double mean = s * invB;
            double var  = s2 * invB - mean * mean;
            double scl  = (double)gamma[w] / sqrt(var + 1e-5);
            sstats[w]     = (float)scl;
            sstats[4 + w] = (float)((double)beta[w] - mean * scl);
        }
    }
    __syncthreads();

    const int b = blockIdx.x * 256 + tid;
    float4 v = ((float4*)out)[b];
    v.x = v.x * sstats[0] + sstats[4];
    v.y = v.y * sstats[1] + sstats[5];
    v.z = v.z * sstats[2] + sstats[6];
    v.w = v.w * sstats[3] + sstats[7];
    ((float4*)out)[b] = v;
}

extern "C" void kernel_launch(void* const* d_in, const int* in_sizes, int n_in,
                              void* d_out, int out_size, void* d_ws, size_t ws_size,
                              hipStream_t stream)
{
    const float* x  = (const float*)d_in[0];   // [B,1,28,28] f32
    const float* qp = (const float*)d_in[1];   // [2,4,2]
    const float* gm = (const float*)d_in[2];   // [4]
    const float* bt = (const float*)d_in[3];   // [4]
    float* out = (float*)d_out;                // [B,4] f32

    const int B    = in_sizes[0] / 784;        // 131072
    const int nblk = B / 256;                  // 512 (2 blocks/CU, all resident)

    float* partials = (float*)d_ws;            // nblk*8 floats = 16 KB

    qfc_main    <<<nblk, 256, 0, stream>>>(x, qp, out, partials);
    qfc_stats_bn<<<nblk, 256, 0, stream>>>(partials, gm, bt, out, nblk, B);
}